// Round 5
// baseline (231.824 us; speedup 1.0000x reference)
//
#include <hip/hip_runtime.h>
#include <cstdint>

// B=4, D=32, HW=262144, C=8 cats, S=4 segs/cat, P=8192 px/segment.
// seg id = flat/P (stable-sort order == identity), cat = seg/4.
#define C_ 8
#define Bn 4
#define Dn 32
#define HWn 262144
#define Pn 8192
#define COUNTF 33558528.0f     // P*(P+1)/2
#define CNT_PER_CAT 131072.0f  // B*HW/C

// ws layout: bf16 intermediate (ushort elems) at offset 0:
//   [bc=32][chunk=32][seg=4][dim=32][pos=256]  = 16M ushort = 32 MB
// then float regions:
#define WS_SUM  16777216            // [1024][4][32] chunk seg-sums per dim
#define WS_PART (WS_SUM + 131072)   // [1024][8]     0-5: pair partials
#define WS_DG   (WS_PART + 8192)    // [32][4][32]   per (bc,seg,chunk) sum||v||^2
#define WS_ERR  (WS_DG + 4096)      // [32][4][32]   per (bc,seg,chunk) radius err
#define WS_BC   (WS_ERR + 4096)     // [32][3]       per-(b,c): err, pos, neg

__device__ __forceinline__ float wred(float x){
  #pragma unroll
  for (int off = 32; off; off >>= 1) x += __shfl_xor(x, off, 64);
  return x;
}

#define UNPK_LO(w) __uint_as_float((w) << 16)
#define UNPK_HI(w) __uint_as_float((w) & 0xffff0000u)

// one ordered position: add to inclusive prefixes, then 6 pair FMAs
#define STEP(a0,a1,a2,a3) { \
  r0 += a0; r1 += a1; r2 += a2; r3 += a3; \
  p01 = fmaf(r0,a1,p01); p02 = fmaf(r0,a2,p02); p03 = fmaf(r0,a3,p03); \
  p12 = fmaf(r1,a2,p12); p13 = fmaf(r1,a3,p13); p23 = fmaf(r2,a3,p23); }

#define STEPW(w0,w1,w2,w3) { \
  STEP(UNPK_LO(w0), UNPK_LO(w1), UNPK_LO(w2), UNPK_LO(w3)); \
  STEP(UNPK_HI(w0), UNPK_HI(w1), UNPK_HI(w2), UNPK_HI(w3)); }

// kS: pure streaming. block = (bc, seg j, range r of 1024 pos); thread owns 4
// consecutive positions x 32 dims (float4 loads). f32 norms -> err + Dg
// (per-wave partials), normalized v packed to bf16 by TRUNCATION (hi16) and
// written to the transposed intermediate. No LDS, no barriers.
__global__ __launch_bounds__(256) void kS(const float* __restrict__ src, float* __restrict__ ws){
  const int tid = threadIdx.x;
  const int blk = blockIdx.x;        // ((bc*4 + j)*8 + r)
  const int r = blk & 7;
  const int j = (blk >> 3) & 3;
  const int bc = blk >> 5;
  const int b = bc >> 3, c = bc & 7;
  const int w = tid >> 6;            // wave id -> chunk k = r*4 + w
  const int k = (r << 2) | w;
  const int pos = (r << 10) + tid * 4;     // position within segment
  const float radius = 1.0f + (float)c;

  const float* base = src + (size_t)b*Dn*HWn + (size_t)(c*4+j)*Pn + pos;
  float4 x[32];
  #pragma unroll
  for (int d = 0; d < 32; ++d) x[d] = *reinterpret_cast<const float4*>(base + (size_t)d*HWn);

  float n0=0.f, n1=0.f, n2=0.f, n3=0.f;
  #pragma unroll
  for (int d = 0; d < 32; ++d){
    n0 = fmaf(x[d].x, x[d].x, n0); n1 = fmaf(x[d].y, x[d].y, n1);
    n2 = fmaf(x[d].z, x[d].z, n2); n3 = fmaf(x[d].w, x[d].w, n3);
  }
  float m0 = sqrtf(n0), m1 = sqrtf(n1), m2 = sqrtf(n2), m3 = sqrtf(n3);
  float i0 = 1.0f/(m0+1e-6f), i1 = 1.0f/(m1+1e-6f);
  float i2 = 1.0f/(m2+1e-6f), i3 = 1.0f/(m3+1e-6f);
  float e0 = m0-radius, e1 = m1-radius, e2 = m2-radius, e3 = m3-radius;
  float errAcc = fmaf(e0,e0, fmaf(e1,e1, fmaf(e2,e2, e3*e3)));
  float dgAcc  = fmaf(n0*i0,i0, fmaf(n1*i1,i1, fmaf(n2*i2,i2, (n3*i3)*i3)));

  unsigned short* vbase = (unsigned short*)ws;
  const size_t eoff = ((((size_t)bc*32 + k)*4 + j)*32)*256 + (pos & 255);
  #pragma unroll
  for (int d = 0; d < 32; ++d){
    uint2 u;
    u.x = (__float_as_uint(x[d].x*i0) >> 16) | (__float_as_uint(x[d].y*i1) & 0xffff0000u);
    u.y = (__float_as_uint(x[d].z*i2) >> 16) | (__float_as_uint(x[d].w*i3) & 0xffff0000u);
    *reinterpret_cast<uint2*>(vbase + eoff + (size_t)d*256) = u;
  }

  float er = wred(errAcc);
  float dg = wred(dgAcc);
  if ((tid & 63) == 0){
    ws[WS_DG  + bc*128 + j*32 + k] = dg;
    ws[WS_ERR + bc*128 + j*32 + k] = er;
  }
}

// kP: block = (bc, chunk k of 256 positions). Thread (dim d, 32-pos subblock
// s) reads the bf16 intermediate (L3-warm), serial in-register prefix + pair
// FMAs -> subblock-local triu; cross-subblock carries in phase 3 (wave 0).
__global__ __launch_bounds__(256) void kP(float* __restrict__ ws){
  __shared__ float lsum[4][32][8];
  __shared__ float redbuf[4][6];
  const int tid = threadIdx.x;
  const int blk = blockIdx.x;        // bc*32 + k
  const int d = tid & 31;
  const int s = tid >> 5;

  const unsigned short* vb = (const unsigned short*)ws;
  float r0=0,r1=0,r2=0,r3=0;
  float p01=0,p02=0,p03=0,p12=0,p13=0,p23=0;
  {
    const uint4* s0p = (const uint4*)(vb + (((size_t)blk*4 + 0)*32 + d)*256 + 32*s);
    const uint4* s1p = (const uint4*)(vb + (((size_t)blk*4 + 1)*32 + d)*256 + 32*s);
    const uint4* s2p = (const uint4*)(vb + (((size_t)blk*4 + 2)*32 + d)*256 + 32*s);
    const uint4* s3p = (const uint4*)(vb + (((size_t)blk*4 + 3)*32 + d)*256 + 32*s);
    #pragma unroll
    for (int g = 0; g < 4; ++g){
      uint4 A = s0p[g], B = s1p[g], Cq = s2p[g], Dq = s3p[g];
      STEPW(A.x, B.x, Cq.x, Dq.x);
      STEPW(A.y, B.y, Cq.y, Dq.y);
      STEPW(A.z, B.z, Cq.z, Dq.z);
      STEPW(A.w, B.w, Cq.w, Dq.w);
    }
  }
  lsum[0][d][s] = r0; lsum[1][d][s] = r1; lsum[2][d][s] = r2; lsum[3][d][s] = r3;

  p01 = wred(p01); p02 = wred(p02); p03 = wred(p03);
  p12 = wred(p12); p13 = wred(p13); p23 = wred(p23);
  if ((tid & 63) == 0){
    const int w = tid >> 6;
    redbuf[w][0]=p01; redbuf[w][1]=p02; redbuf[w][2]=p03;
    redbuf[w][3]=p12; redbuf[w][4]=p13; redbuf[w][5]=p23;
  }
  __syncthreads();
  if (tid >= 64) return;

  // phase 3 (wave 0; halves duplicate dim work, halve after wred)
  float c0=0,c1=0,c2=0,c3=0;
  float x01=0,x02=0,x03=0,x12=0,x13=0,x23=0;
  {
    const int dd = tid & 31;
    #pragma unroll
    for (int ss = 0; ss < 8; ++ss){
      float a0=lsum[0][dd][ss], a1=lsum[1][dd][ss], a2=lsum[2][dd][ss], a3=lsum[3][dd][ss];
      x01=fmaf(c0,a1,x01); x02=fmaf(c0,a2,x02); x03=fmaf(c0,a3,x03);
      x12=fmaf(c1,a2,x12); x13=fmaf(c1,a3,x13); x23=fmaf(c2,a3,x23);
      c0+=a0; c1+=a1; c2+=a2; c3+=a3;
    }
    if (tid < 32){
      float* sp = ws + WS_SUM + (size_t)blk*128 + dd;
      sp[0]=c0; sp[32]=c1; sp[64]=c2; sp[96]=c3;
    }
  }
  x01 = 0.5f*wred(x01); x02 = 0.5f*wred(x02); x03 = 0.5f*wred(x03);
  x12 = 0.5f*wred(x12); x13 = 0.5f*wred(x13); x23 = 0.5f*wred(x23);
  if (tid == 0){
    float* pp = ws + WS_PART + (size_t)blk*8;
    pp[0] = redbuf[0][0]+redbuf[1][0]+redbuf[2][0]+redbuf[3][0] + x01;
    pp[1] = redbuf[0][1]+redbuf[1][1]+redbuf[2][1]+redbuf[3][1] + x02;
    pp[2] = redbuf[0][2]+redbuf[1][2]+redbuf[2][2]+redbuf[3][2] + x03;
    pp[3] = redbuf[0][3]+redbuf[1][3]+redbuf[2][3]+redbuf[3][3] + x12;
    pp[4] = redbuf[0][4]+redbuf[1][4]+redbuf[2][4]+redbuf[3][4] + x13;
    pp[5] = redbuf[0][5]+redbuf[1][5]+redbuf[2][5]+redbuf[3][5] + x23;
  }
}

// kB: one 64-thread block per (b,c). Cross-chunk carry pass over 32 chunk
// sums (lane = dim, halves duplicate -> 0.5x after wred) + fold of per-chunk
// pair partials and kS's Dg/err partials. Emits {err, pos, neg}.
__global__ __launch_bounds__(64) void kB(float* __restrict__ ws){
  const int bc = blockIdx.x;
  const int lane = threadIdx.x;
  const int d = lane & 31;
  float c0=0,c1=0,c2=0,c3=0;
  float x01=0,x02=0,x03=0,x12=0,x13=0,x23=0;
  #pragma unroll 4
  for (int k = 0; k < 32; ++k){
    const float* sp = ws + WS_SUM + (size_t)(bc*32+k)*128 + d;
    float a0=sp[0], a1=sp[32], a2=sp[64], a3=sp[96];
    x01=fmaf(c0,a1,x01); x02=fmaf(c0,a2,x02); x03=fmaf(c0,a3,x03);
    x12=fmaf(c1,a2,x12); x13=fmaf(c1,a3,x13); x23=fmaf(c2,a3,x23);
    c0+=a0; c1+=a1; c2+=a2; c3+=a3;
  }
  float T0 = 0.5f*wred(c0*c0), T1 = 0.5f*wred(c1*c1);
  float T2 = 0.5f*wred(c2*c2), T3 = 0.5f*wred(c3*c3);
  x01=0.5f*wred(x01); x02=0.5f*wred(x02); x03=0.5f*wred(x03);
  x12=0.5f*wred(x12); x13=0.5f*wred(x13); x23=0.5f*wred(x23);

  const float* pp = ws + WS_PART + (size_t)(bc*32 + d)*8;
  float q0 = 0.5f*wred(pp[0]), q1 = 0.5f*wred(pp[1]), q2 = 0.5f*wred(pp[2]);
  float q3 = 0.5f*wred(pp[3]), q4 = 0.5f*wred(pp[4]), q5 = 0.5f*wred(pp[5]);

  const float* dgp = ws + WS_DG  + bc*128;
  const float* erp = ws + WS_ERR + bc*128;
  float g0 = 0.5f*wred(dgp[d]),    g1 = 0.5f*wred(dgp[32+d]);
  float g2 = 0.5f*wred(dgp[64+d]), g3 = 0.5f*wred(dgp[96+d]);
  float er = 0.5f*wred(erp[d] + erp[32+d] + erp[64+d] + erp[96+d]);

  if (lane == 0){
    const float inv2c = 1.0f/(2.0f*COUNTF);
    const float invc  = 1.0f/COUNTF;
    float pos = (1.0f-(T0+g0)*inv2c) + (1.0f-(T1+g1)*inv2c)
              + (1.0f-(T2+g2)*inv2c) + (1.0f-(T3+g3)*inv2c);
    float neg = ((x01+q0)*invc + 2.0f) + ((x02+q1)*invc + 2.0f) + ((x03+q2)*invc + 2.0f)
              + ((x12+q3)*invc + 2.0f) + ((x13+q4)*invc + 2.0f) + ((x23+q5)*invc + 2.0f);
    float* o = ws + WS_BC + bc*3;
    o[0]=er; o[1]=pos; o[2]=neg;
  }
}

// kC: fold 32 (b,c) partials into the scalar loss.
__global__ __launch_bounds__(64) void kC(const float* __restrict__ ws, float* __restrict__ out){
  const int lane = threadIdx.x;
  float er = 0.f, pn = 0.f;
  if (lane < 32){
    const float* o = ws + WS_BC + lane*3;
    er = o[0]; pn = o[1] + o[2];
  }
  float sv = pn;
  #pragma unroll
  for (int off = 32; off; off >>= 1) sv += __shfl_xor(sv, off, 64);
  er += __shfl_xor(er, 8, 64);
  er += __shfl_xor(er, 16, 64);
  float r = (lane >= 1 && lane < 8) ? (er / CNT_PER_CAT) : 0.0f;  // skip cat 0
  r += __shfl_xor(r, 1, 64);
  r += __shfl_xor(r, 2, 64);
  r += __shfl_xor(r, 4, 64);
  if (lane == 0){
    float radius_loss = r / 7.0f;          // mean over cats 1..7
    float sim = sv / 320.0f;               // B*C*(S + S*(S-1)/2)
    out[0] = 0.5f*radius_loss + 0.5f*sim;
  }
}

extern "C" void kernel_launch(void* const* d_in, const int* in_sizes, int n_in,
                              void* d_out, int out_size, void* d_ws, size_t ws_size,
                              hipStream_t stream){
  const float* outputs = (const float*)d_in[0];   // [4][32][512][512] f32
  float* ws  = (float*)d_ws;                      // ~68 MB used
  float* out = (float*)d_out;                     // 1 float
  kS<<<1024, 256, 0, stream>>>(outputs, ws);
  kP<<<1024, 256, 0, stream>>>(ws);
  kB<<<32, 64, 0, stream>>>(ws);
  kC<<<1, 64, 0, stream>>>(ws, out);
}

// Round 6
// 202.879 us; speedup vs baseline: 1.1427x; 1.1427x over previous
//
#include <hip/hip_runtime.h>
#include <cstdint>

// B=4, D=32, HW=262144, C=8 cats, S=4 segs/cat, P=8192 px/segment.
// seg id = flat/P (stable-sort order == identity), cat = seg/4.
#define C_ 8
#define Bn 4
#define Dn 32
#define HWn 262144
#define Pn 8192
#define CH 128                 // positions per chunk (one 256-thread block)
#define NCH 64                 // chunks per segment
#define NBLK (Bn*C_*NCH)       // 2048 kA blocks
#define RL 136                 // vbuf row length (pad 8: 16B-aligned, conflict-free)
#define COUNTF 33558528.0f     // P*(P+1)/2
#define CNT_PER_CAT 131072.0f  // B*HW/C

// ws float offsets (all written before read; no atomics)
#define WS_SUM 0                        // [NBLK][4][32]  chunk seg-sums per dim
#define WS_PART (NBLK*4*32)             // [NBLK][16]     0-5 pair,6-9 dg,10 err
#define WS_BC (WS_PART + NBLK*16)       // [32][3]        per-(b,c) err,pos,neg

__device__ __forceinline__ float wred(float x){
  #pragma unroll
  for (int off = 32; off; off >>= 1) x += __shfl_xor(x, off, 64);
  return x;
}

#define UNPK_LO(w) __uint_as_float((w) << 16)
#define UNPK_HI(w) __uint_as_float((w) & 0xffff0000u)

// one ordered position: add to inclusive prefixes, then 6 pair FMAs
#define STEP(a0,a1,a2,a3) { \
  r0 += a0; r1 += a1; r2 += a2; r3 += a3; \
  p01 = fmaf(r0,a1,p01); p02 = fmaf(r0,a2,p02); p03 = fmaf(r0,a3,p03); \
  p12 = fmaf(r1,a2,p12); p13 = fmaf(r1,a3,p13); p23 = fmaf(r2,a3,p23); }

#define STEPW(w0,w1,w2,w3) { \
  STEP(UNPK_LO(w0), UNPK_LO(w1), UNPK_LO(w2), UNPK_LO(w3)); \
  STEP(UNPK_HI(w0), UNPK_HI(w1), UNPK_HI(w2), UNPK_HI(w3)); }

// kA: block = (b, c, chunk of 128 positions). ~39KB LDS -> 4 blocks/CU (50% occ).
// Phase1: wave j owns seg j; thread (j,l) loads float2 (2 consecutive positions)
//   for all 32 dims. Thread-local norms -> err + Dg partials. Normalized v
//   packed (truncation) as one dword per dim -> transposed vbuf[seg][dim][pos],
//   conflict-free (banks = (4d + l) mod 32, 2 lanes/bank).
// Phase2 (thread=(dim d, 16-pos subblock s)): serial in-register prefix + pair
//   FMAs over 16 positions -> subblock-local triu; subblock seg-sums to lsum.
// Phase3 (wave 0): cross-subblock carries + chunk totals -> ws.
__global__ __launch_bounds__(256, 4) void kA(const float* __restrict__ src, float* __restrict__ ws){
  __shared__ __align__(16) unsigned short vbuf[4][32][RL];
  __shared__ float lsum[4][32][8];
  __shared__ float redbuf[4][8];      // [wave]: 0-5 pair, 6 dg(seg=wave), 7 err
  const int tid = threadIdx.x;
  const int blk = blockIdx.x;
  const int bc = blk >> 6;            // b*8 + c
  const int k = blk & 63;
  const int b = bc >> 3;
  const int c = bc & 7;
  const int j = tid >> 6;             // seg = wave id
  const int l = tid & 63;
  const float radius = 1.0f + (float)c;

  // ---- phase 1
  float errAcc, dgAcc;
  {
    const float* gp = src + (size_t)b*Dn*HWn + (size_t)(c*4+j)*Pn + (k<<7) + (l<<1);
    float2 x[32];
    #pragma unroll
    for (int d = 0; d < 32; ++d) x[d] = *reinterpret_cast<const float2*>(gp + (size_t)d*HWn);
    float n0=0.f, n1=0.f;
    #pragma unroll
    for (int d = 0; d < 32; ++d){
      n0 = fmaf(x[d].x, x[d].x, n0); n1 = fmaf(x[d].y, x[d].y, n1);
    }
    float m0 = sqrtf(n0), m1 = sqrtf(n1);
    float i0 = 1.0f/(m0+1e-6f), i1 = 1.0f/(m1+1e-6f);
    float e0 = m0-radius, e1 = m1-radius;
    errAcc = fmaf(e0,e0, e1*e1);
    dgAcc  = fmaf(n0*i0,i0, (n1*i1)*i1);
    #pragma unroll
    for (int d = 0; d < 32; ++d){
      unsigned int u = (__float_as_uint(x[d].x*i0) >> 16) | (__float_as_uint(x[d].y*i1) & 0xffff0000u);
      *reinterpret_cast<unsigned int*>(&vbuf[j][d][2*l]) = u;
    }
  }
  __syncthreads();

  // ---- phase 2
  const int d = tid & 31;
  const int s = tid >> 5;
  float r0=0,r1=0,r2=0,r3=0;
  float p01=0,p02=0,p03=0,p12=0,p13=0,p23=0;
  {
    const uint4* s0p = (const uint4*)&vbuf[0][d][16*s];
    const uint4* s1p = (const uint4*)&vbuf[1][d][16*s];
    const uint4* s2p = (const uint4*)&vbuf[2][d][16*s];
    const uint4* s3p = (const uint4*)&vbuf[3][d][16*s];
    #pragma unroll
    for (int g = 0; g < 2; ++g){
      uint4 A = s0p[g], B = s1p[g], Cq = s2p[g], Dq = s3p[g];
      STEPW(A.x, B.x, Cq.x, Dq.x);
      STEPW(A.y, B.y, Cq.y, Dq.y);
      STEPW(A.z, B.z, Cq.z, Dq.z);
      STEPW(A.w, B.w, Cq.w, Dq.w);
    }
  }
  lsum[0][d][s] = r0; lsum[1][d][s] = r1; lsum[2][d][s] = r2; lsum[3][d][s] = r3;

  p01 = wred(p01); p02 = wred(p02); p03 = wred(p03);
  p12 = wred(p12); p13 = wred(p13); p23 = wred(p23);
  float dg = wred(dgAcc);
  float er = wred(errAcc);
  if ((tid & 63) == 0){
    const int w = tid >> 6;
    redbuf[w][0]=p01; redbuf[w][1]=p02; redbuf[w][2]=p03;
    redbuf[w][3]=p12; redbuf[w][4]=p13; redbuf[w][5]=p23;
    redbuf[w][6]=dg;  redbuf[w][7]=er;
  }
  __syncthreads();
  if (tid >= 64) return;

  // ---- phase 3 (wave 0; both halves duplicate dim work, halve after wred)
  float c0=0,c1=0,c2=0,c3=0;
  float x01=0,x02=0,x03=0,x12=0,x13=0,x23=0;
  {
    const int dd = tid & 31;
    #pragma unroll
    for (int ss = 0; ss < 8; ++ss){
      float a0=lsum[0][dd][ss], a1=lsum[1][dd][ss], a2=lsum[2][dd][ss], a3=lsum[3][dd][ss];
      x01=fmaf(c0,a1,x01); x02=fmaf(c0,a2,x02); x03=fmaf(c0,a3,x03);
      x12=fmaf(c1,a2,x12); x13=fmaf(c1,a3,x13); x23=fmaf(c2,a3,x23);
      c0+=a0; c1+=a1; c2+=a2; c3+=a3;
    }
    if (tid < 32){
      float* sp = ws + WS_SUM + (size_t)blk*128 + dd;
      sp[0]=c0; sp[32]=c1; sp[64]=c2; sp[96]=c3;
    }
  }
  x01 = 0.5f*wred(x01); x02 = 0.5f*wred(x02); x03 = 0.5f*wred(x03);
  x12 = 0.5f*wred(x12); x13 = 0.5f*wred(x13); x23 = 0.5f*wred(x23);
  if (tid == 0){
    float* pp = ws + WS_PART + (size_t)blk*16;
    pp[0] = redbuf[0][0]+redbuf[1][0]+redbuf[2][0]+redbuf[3][0] + x01;
    pp[1] = redbuf[0][1]+redbuf[1][1]+redbuf[2][1]+redbuf[3][1] + x02;
    pp[2] = redbuf[0][2]+redbuf[1][2]+redbuf[2][2]+redbuf[3][2] + x03;
    pp[3] = redbuf[0][3]+redbuf[1][3]+redbuf[2][3]+redbuf[3][3] + x12;
    pp[4] = redbuf[0][4]+redbuf[1][4]+redbuf[2][4]+redbuf[3][4] + x13;
    pp[5] = redbuf[0][5]+redbuf[1][5]+redbuf[2][5]+redbuf[3][5] + x23;
    pp[6] = redbuf[0][6]; pp[7] = redbuf[1][6];
    pp[8] = redbuf[2][6]; pp[9] = redbuf[3][6];
    pp[10] = redbuf[0][7]+redbuf[1][7]+redbuf[2][7]+redbuf[3][7];
  }
}

// kB: one 64-thread block per (b,c). Cross-chunk carry pass over 64 chunk
// sums (lane = dim, duplicated across halves -> 0.5x after wred); per-chunk
// partial folds with lane = chunk (64 lanes = 64 chunks, direct wred sum).
__global__ __launch_bounds__(64) void kB(float* __restrict__ ws){
  const int bc = blockIdx.x;
  const int lane = threadIdx.x;
  const int d = lane & 31;
  float c0=0,c1=0,c2=0,c3=0;
  float x01=0,x02=0,x03=0,x12=0,x13=0,x23=0;
  #pragma unroll 4
  for (int k = 0; k < NCH; ++k){
    const float* sp = ws + WS_SUM + (size_t)(bc*NCH+k)*128 + d;
    float a0=sp[0], a1=sp[32], a2=sp[64], a3=sp[96];
    x01=fmaf(c0,a1,x01); x02=fmaf(c0,a2,x02); x03=fmaf(c0,a3,x03);
    x12=fmaf(c1,a2,x12); x13=fmaf(c1,a3,x13); x23=fmaf(c2,a3,x23);
    c0+=a0; c1+=a1; c2+=a2; c3+=a3;
  }
  float T0 = 0.5f*wred(c0*c0), T1 = 0.5f*wred(c1*c1);
  float T2 = 0.5f*wred(c2*c2), T3 = 0.5f*wred(c3*c3);
  x01=0.5f*wred(x01); x02=0.5f*wred(x02); x03=0.5f*wred(x03);
  x12=0.5f*wred(x12); x13=0.5f*wred(x13); x23=0.5f*wred(x23);

  const float* pp = ws + WS_PART + (size_t)(bc*NCH + lane)*16;  // lane = chunk
  float q0 = wred(pp[0]), q1 = wred(pp[1]), q2 = wred(pp[2]);
  float q3 = wred(pp[3]), q4 = wred(pp[4]), q5 = wred(pp[5]);
  float q6 = wred(pp[6]), q7 = wred(pp[7]), q8 = wred(pp[8]);
  float q9 = wred(pp[9]), q10 = wred(pp[10]);

  if (lane == 0){
    const float inv2c = 1.0f/(2.0f*COUNTF);
    const float invc  = 1.0f/COUNTF;
    float pos = (1.0f-(T0+q6)*inv2c) + (1.0f-(T1+q7)*inv2c)
              + (1.0f-(T2+q8)*inv2c) + (1.0f-(T3+q9)*inv2c);
    float neg = ((x01+q0)*invc + 2.0f) + ((x02+q1)*invc + 2.0f) + ((x03+q2)*invc + 2.0f)
              + ((x12+q3)*invc + 2.0f) + ((x13+q4)*invc + 2.0f) + ((x23+q5)*invc + 2.0f);
    float* o = ws + WS_BC + bc*3;
    o[0]=q10; o[1]=pos; o[2]=neg;
  }
}

// kC: fold 32 (b,c) partials into the scalar loss.
__global__ __launch_bounds__(64) void kC(const float* __restrict__ ws, float* __restrict__ out){
  const int lane = threadIdx.x;
  float er = 0.f, pn = 0.f;
  if (lane < 32){
    const float* o = ws + WS_BC + lane*3;
    er = o[0]; pn = o[1] + o[2];
  }
  float sv = pn;
  #pragma unroll
  for (int off = 32; off; off >>= 1) sv += __shfl_xor(sv, off, 64);
  er += __shfl_xor(er, 8, 64);
  er += __shfl_xor(er, 16, 64);
  float r = (lane >= 1 && lane < 8) ? (er / CNT_PER_CAT) : 0.0f;  // skip cat 0
  r += __shfl_xor(r, 1, 64);
  r += __shfl_xor(r, 2, 64);
  r += __shfl_xor(r, 4, 64);
  if (lane == 0){
    float radius_loss = r / 7.0f;          // mean over cats 1..7
    float sim = sv / 320.0f;               // B*C*(S + S*(S-1)/2)
    out[0] = 0.5f*radius_loss + 0.5f*sim;
  }
}

extern "C" void kernel_launch(void* const* d_in, const int* in_sizes, int n_in,
                              void* d_out, int out_size, void* d_ws, size_t ws_size,
                              hipStream_t stream){
  const float* outputs = (const float*)d_in[0];   // [4][32][512][512] f32
  float* ws  = (float*)d_ws;                      // ~1.2 MB used
  float* out = (float*)d_out;                     // 1 float
  kA<<<NBLK, 256, 0, stream>>>(outputs, ws);
  kB<<<32, 64, 0, stream>>>(ws);
  kC<<<1, 64, 0, stream>>>(ws, out);
}

// Round 8
// 197.483 us; speedup vs baseline: 1.1739x; 1.0273x over previous
//
#include <hip/hip_runtime.h>
#include <cstdint>

// B=4, D=32, HW=262144, C=8 cats, S=4 segs/cat, P=8192 px/segment.
// seg id = flat/P (stable-sort order == identity), cat = seg/4.
#define C_ 8
#define Bn 4
#define Dn 32
#define HWn 262144
#define Pn 8192
#define CH 256                 // positions per chunk (one 256-thread block)
#define NCH 32                 // chunks per segment
#define NBLK (Bn*C_*NCH)       // 1024 kA blocks
#define COUNTF 33558528.0f     // P*(P+1)/2
#define CNT_PER_CAT 131072.0f  // B*HW/C

// ws float offsets (all written before read; no atomics)
#define WS_SUM 0                        // [NBLK][4][32]  chunk seg-sums per dim
#define WS_PART (NBLK*4*32)             // [NBLK][16]     0-5 pair,6-9 dg,10 err
#define WS_BC (WS_PART + NBLK*16)       // [32][3]        per-(b,c) err,pos,neg

__device__ __forceinline__ float wred(float x){
  #pragma unroll
  for (int off = 32; off; off >>= 1) x += __shfl_xor(x, off, 64);
  return x;
}

#define UNPK_LO(w) __uint_as_float((w) << 16)
#define UNPK_HI(w) __uint_as_float((w) & 0xffff0000u)

// one ordered position: add to inclusive prefixes, then 6 pair FMAs
#define STEP(a0,a1,a2,a3) { \
  r0 += a0; r1 += a1; r2 += a2; r3 += a3; \
  p01 = fmaf(r0,a1,p01); p02 = fmaf(r0,a2,p02); p03 = fmaf(r0,a3,p03); \
  p12 = fmaf(r1,a2,p12); p13 = fmaf(r1,a3,p13); p23 = fmaf(r2,a3,p23); }

#define STEPW(w0,w1,w2,w3) { \
  STEP(UNPK_LO(w0), UNPK_LO(w1), UNPK_LO(w2), UNPK_LO(w3)); \
  STEP(UNPK_HI(w0), UNPK_HI(w1), UNPK_HI(w2), UNPK_HI(w3)); }

// kA: block = (b, c, chunk of 256 positions). R4 structure, launch_bounds
// relaxed to 2 waves/EU so all 32 dwordx4 payload loads stay in flight.
__global__ __launch_bounds__(256, 2) void kA(const float* __restrict__ src, float* __restrict__ ws){
  __shared__ __align__(16) unsigned short vbuf[4][32][264];
  __shared__ float lsum[4][32][8];
  __shared__ float redbuf[4][8];      // [wave]: 0-5 pair, 6 dg(seg=wave), 7 err
  const int tid = threadIdx.x;
  const int blk = blockIdx.x;
  const int b = blk >> 8;
  const int c = (blk >> 5) & 7;
  const int k = blk & 31;
  const int j = tid >> 6;             // seg = wave id
  const int l = tid & 63;
  const float radius = 1.0f + (float)c;

  // ---- phase 1: 32 independent float4 loads, then norms, then packed store
  float errAcc, dgAcc;
  {
    const float* gp = src + (size_t)b*Dn*HWn + (size_t)(c*4+j)*Pn + (k<<8) + (l<<2);
    float4 x[32];
    #pragma unroll
    for (int d = 0; d < 32; ++d) x[d] = *reinterpret_cast<const float4*>(gp + (size_t)d*HWn);
    float n0=0.f, n1=0.f, n2=0.f, n3=0.f;
    #pragma unroll
    for (int d = 0; d < 32; ++d){
      n0 = fmaf(x[d].x, x[d].x, n0); n1 = fmaf(x[d].y, x[d].y, n1);
      n2 = fmaf(x[d].z, x[d].z, n2); n3 = fmaf(x[d].w, x[d].w, n3);
    }
    float m0 = sqrtf(n0), m1 = sqrtf(n1), m2 = sqrtf(n2), m3 = sqrtf(n3);
    float i0 = 1.0f/(m0+1e-6f), i1 = 1.0f/(m1+1e-6f);
    float i2 = 1.0f/(m2+1e-6f), i3 = 1.0f/(m3+1e-6f);
    float e0 = m0-radius, e1 = m1-radius, e2 = m2-radius, e3 = m3-radius;
    errAcc = fmaf(e0,e0, fmaf(e1,e1, fmaf(e2,e2, e3*e3)));
    dgAcc  = fmaf(n0*i0,i0, fmaf(n1*i1,i1, fmaf(n2*i2,i2, (n3*i3)*i3)));
    #pragma unroll
    for (int d = 0; d < 32; ++d){
      unsigned int u0 = (__float_as_uint(x[d].x*i0) >> 16) | (__float_as_uint(x[d].y*i1) & 0xffff0000u);
      unsigned int u1 = (__float_as_uint(x[d].z*i2) >> 16) | (__float_as_uint(x[d].w*i3) & 0xffff0000u);
      *reinterpret_cast<uint2*>(&vbuf[j][d][l*4]) = make_uint2(u0, u1);
    }
  }
  __syncthreads();

  // ---- phase 2: thread (dim d, 32-pos subblock s)
  const int d = tid & 31;
  const int s = tid >> 5;
  float r0=0,r1=0,r2=0,r3=0;
  float p01=0,p02=0,p03=0,p12=0,p13=0,p23=0;
  {
    const uint4* s0p = (const uint4*)&vbuf[0][d][32*s];
    const uint4* s1p = (const uint4*)&vbuf[1][d][32*s];
    const uint4* s2p = (const uint4*)&vbuf[2][d][32*s];
    const uint4* s3p = (const uint4*)&vbuf[3][d][32*s];
    #pragma unroll
    for (int g = 0; g < 4; ++g){
      uint4 A = s0p[g], B = s1p[g], Cq = s2p[g], Dq = s3p[g];
      STEPW(A.x, B.x, Cq.x, Dq.x);
      STEPW(A.y, B.y, Cq.y, Dq.y);
      STEPW(A.z, B.z, Cq.z, Dq.z);
      STEPW(A.w, B.w, Cq.w, Dq.w);
    }
  }
  lsum[0][d][s] = r0; lsum[1][d][s] = r1; lsum[2][d][s] = r2; lsum[3][d][s] = r3;

  p01 = wred(p01); p02 = wred(p02); p03 = wred(p03);
  p12 = wred(p12); p13 = wred(p13); p23 = wred(p23);
  float dg = wred(dgAcc);
  float er = wred(errAcc);
  if ((tid & 63) == 0){
    const int w = tid >> 6;
    redbuf[w][0]=p01; redbuf[w][1]=p02; redbuf[w][2]=p03;
    redbuf[w][3]=p12; redbuf[w][4]=p13; redbuf[w][5]=p23;
    redbuf[w][6]=dg;  redbuf[w][7]=er;
  }
  __syncthreads();
  if (tid >= 64) return;

  // ---- phase 3 (wave 0; both halves duplicate dim work, halve after wred)
  float c0=0,c1=0,c2=0,c3=0;
  float x01=0,x02=0,x03=0,x12=0,x13=0,x23=0;
  {
    const int dd = tid & 31;
    #pragma unroll
    for (int ss = 0; ss < 8; ++ss){
      float a0=lsum[0][dd][ss], a1=lsum[1][dd][ss], a2=lsum[2][dd][ss], a3=lsum[3][dd][ss];
      x01=fmaf(c0,a1,x01); x02=fmaf(c0,a2,x02); x03=fmaf(c0,a3,x03);
      x12=fmaf(c1,a2,x12); x13=fmaf(c1,a3,x13); x23=fmaf(c2,a3,x23);
      c0+=a0; c1+=a1; c2+=a2; c3+=a3;
    }
    if (tid < 32){
      float* sp = ws + WS_SUM + (size_t)blk*128 + dd;
      sp[0]=c0; sp[32]=c1; sp[64]=c2; sp[96]=c3;
    }
  }
  x01 = 0.5f*wred(x01); x02 = 0.5f*wred(x02); x03 = 0.5f*wred(x03);
  x12 = 0.5f*wred(x12); x13 = 0.5f*wred(x13); x23 = 0.5f*wred(x23);
  if (tid == 0){
    float* pp = ws + WS_PART + (size_t)blk*16;
    pp[0] = redbuf[0][0]+redbuf[1][0]+redbuf[2][0]+redbuf[3][0] + x01;
    pp[1] = redbuf[0][1]+redbuf[1][1]+redbuf[2][1]+redbuf[3][1] + x02;
    pp[2] = redbuf[0][2]+redbuf[1][2]+redbuf[2][2]+redbuf[3][2] + x03;
    pp[3] = redbuf[0][3]+redbuf[1][3]+redbuf[2][3]+redbuf[3][3] + x12;
    pp[4] = redbuf[0][4]+redbuf[1][4]+redbuf[2][4]+redbuf[3][4] + x13;
    pp[5] = redbuf[0][5]+redbuf[1][5]+redbuf[2][5]+redbuf[3][5] + x23;
    pp[6] = redbuf[0][6]; pp[7] = redbuf[1][6];
    pp[8] = redbuf[2][6]; pp[9] = redbuf[3][6];
    pp[10] = redbuf[0][7]+redbuf[1][7]+redbuf[2][7]+redbuf[3][7];
  }
}

// kB: one 256-thread block per (b,c). Thread (g=tid>>5, d=tid&31):
//   group g walks chunks g*4..g*4+3 (4 serial iters), local carries lc_i;
//   hierarchical cross-group prefix via LDS: x_ij += inc_i(g)*T_j(g).
//   Pair/dg/err partial folds by 32-lane segmented shuffle (thread (g,d):
//   value g (+8+g if g<3) of chunk d). Finalize per-(b,c) {err,pos,neg}.
__global__ __launch_bounds__(256) void kB(float* __restrict__ ws){
  __shared__ float gsum[8][4][32];
  __shared__ float redx[4][10];
  __shared__ float partv[8][2];
  const int tid = threadIdx.x;
  const int bc = blockIdx.x;
  const int g = tid >> 5;
  const int d = tid & 31;

  float lc0=0,lc1=0,lc2=0,lc3=0;
  float x01=0,x02=0,x03=0,x12=0,x13=0,x23=0;
  #pragma unroll
  for (int t = 0; t < 4; ++t){
    const float* sp = ws + WS_SUM + (size_t)(bc*NCH + g*4 + t)*128 + d;
    float a0=sp[0], a1=sp[32], a2=sp[64], a3=sp[96];
    x01=fmaf(lc0,a1,x01); x02=fmaf(lc0,a2,x02); x03=fmaf(lc0,a3,x03);
    x12=fmaf(lc1,a2,x12); x13=fmaf(lc1,a3,x13); x23=fmaf(lc2,a3,x23);
    lc0+=a0; lc1+=a1; lc2+=a2; lc3+=a3;
  }
  gsum[g][0][d]=lc0; gsum[g][1][d]=lc1; gsum[g][2][d]=lc2; gsum[g][3][d]=lc3;

  // partial folds: value set g (and 8+g for g<3) across chunks k=d
  const float* pp = ws + WS_PART + (size_t)(bc*NCH + d)*16;
  float v1 = pp[g];
  float v2 = (g < 3) ? pp[8+g] : 0.0f;
  #pragma unroll
  for (int off = 16; off; off >>= 1){
    v1 += __shfl_xor(v1, off, 64);
    v2 += __shfl_xor(v2, off, 64);
  }
  if (d == 0){ partv[g][0]=v1; partv[g][1]=v2; }
  __syncthreads();

  float inc0=0,inc1=0,inc2=0,inc3=0;
  float tot0=0,tot1=0,tot2=0,tot3=0;
  #pragma unroll
  for (int gg = 0; gg < 8; ++gg){
    float t0=gsum[gg][0][d], t1=gsum[gg][1][d], t2=gsum[gg][2][d], t3=gsum[gg][3][d];
    if (gg < g){ inc0+=t0; inc1+=t1; inc2+=t2; inc3+=t3; }
    tot0+=t0; tot1+=t1; tot2+=t2; tot3+=t3;
  }
  x01=fmaf(inc0,lc1,x01); x02=fmaf(inc0,lc2,x02); x03=fmaf(inc0,lc3,x03);
  x12=fmaf(inc1,lc2,x12); x13=fmaf(inc1,lc3,x13); x23=fmaf(inc2,lc3,x23);
  float t20 = (g==0)? tot0*tot0 : 0.0f;
  float t21 = (g==0)? tot1*tot1 : 0.0f;
  float t22 = (g==0)? tot2*tot2 : 0.0f;
  float t23 = (g==0)? tot3*tot3 : 0.0f;

  x01=wred(x01); x02=wred(x02); x03=wred(x03);
  x12=wred(x12); x13=wred(x13); x23=wred(x23);
  t20=wred(t20); t21=wred(t21); t22=wred(t22); t23=wred(t23);
  if ((tid & 63) == 0){
    const int w = tid >> 6;
    redx[w][0]=x01; redx[w][1]=x02; redx[w][2]=x03;
    redx[w][3]=x12; redx[w][4]=x13; redx[w][5]=x23;
    redx[w][6]=t20; redx[w][7]=t21; redx[w][8]=t22; redx[w][9]=t23;
  }
  __syncthreads();
  if (tid == 0){
    float X[10];
    #pragma unroll
    for (int v = 0; v < 10; ++v)
      X[v] = redx[0][v]+redx[1][v]+redx[2][v]+redx[3][v];
    // partv mapping: values 0-5 pair, 6-7 dg0/dg1 (partv[6/7][0]),
    // 8-9 dg2/dg3 (partv[0/1][1]), 10 err (partv[2][1])
    float q0=partv[0][0], q1=partv[1][0], q2=partv[2][0];
    float q3=partv[3][0], q4=partv[4][0], q5=partv[5][0];
    float dg0=partv[6][0], dg1=partv[7][0], dg2=partv[0][1], dg3=partv[1][1];
    float er=partv[2][1];
    const float inv2c = 1.0f/(2.0f*COUNTF);
    const float invc  = 1.0f/COUNTF;
    float pos = (1.0f-(X[6]+dg0)*inv2c) + (1.0f-(X[7]+dg1)*inv2c)
              + (1.0f-(X[8]+dg2)*inv2c) + (1.0f-(X[9]+dg3)*inv2c);
    float neg = ((X[0]+q0)*invc + 2.0f) + ((X[1]+q1)*invc + 2.0f) + ((X[2]+q2)*invc + 2.0f)
              + ((X[3]+q3)*invc + 2.0f) + ((X[4]+q4)*invc + 2.0f) + ((X[5]+q5)*invc + 2.0f);
    float* o = ws + WS_BC + bc*3;
    o[0]=er; o[1]=pos; o[2]=neg;
  }
}

// kC: fold 32 (b,c) partials into the scalar loss.
__global__ __launch_bounds__(64) void kC(const float* __restrict__ ws, float* __restrict__ out){
  const int lane = threadIdx.x;
  float er = 0.f, pn = 0.f;
  if (lane < 32){
    const float* o = ws + WS_BC + lane*3;
    er = o[0]; pn = o[1] + o[2];
  }
  float sv = pn;
  #pragma unroll
  for (int off = 32; off; off >>= 1) sv += __shfl_xor(sv, off, 64);
  er += __shfl_xor(er, 8, 64);
  er += __shfl_xor(er, 16, 64);
  float r = (lane >= 1 && lane < 8) ? (er / CNT_PER_CAT) : 0.0f;  // skip cat 0
  r += __shfl_xor(r, 1, 64);
  r += __shfl_xor(r, 2, 64);
  r += __shfl_xor(r, 4, 64);
  if (lane == 0){
    float radius_loss = r / 7.0f;          // mean over cats 1..7
    float sim = sv / 320.0f;               // B*C*(S + S*(S-1)/2)
    out[0] = 0.5f*radius_loss + 0.5f*sim;
  }
}

extern "C" void kernel_launch(void* const* d_in, const int* in_sizes, int n_in,
                              void* d_out, int out_size, void* d_ws, size_t ws_size,
                              hipStream_t stream){
  const float* outputs = (const float*)d_in[0];   // [4][32][512][512] f32
  float* ws  = (float*)d_ws;                      // ~590 KB used
  float* out = (float*)d_out;                     // 1 float
  kA<<<NBLK, 256, 0, stream>>>(outputs, ws);
  kB<<<32, 256, 0, stream>>>(ws);
  kC<<<1, 64, 0, stream>>>(ws, out);
}